// Round 2
// baseline (583.621 us; speedup 1.0000x reference)
//
#include <hip/hip_runtime.h>

#define NBINS 4096
#define CAP   (1 << 20)   // candidate buffer capacity (4 MiB)

struct Ws {
  unsigned bins[NBINS];   // pass-1 histogram (global)
  unsigned ncand;         // compacted candidate count
  unsigned b1;            // selected high-12-bit bin
  unsigned krem;          // remaining rank within bin b1
  unsigned cand[CAP];     // candidate |x| bit patterns
};

// ---------- init: zero histogram + candidate counter ----------
__global__ __launch_bounds__(256) void init_kernel(Ws* ws) {
  int t = threadIdx.x;
  for (int j = t; j < NBINS; j += 256) ws->bins[j] = 0u;
  if (t == 0) ws->ncand = 0u;
}

// ---------- fused SiLU + pass-1 histogram ----------
// grid-stride over all n/4 float4s; iteration 0 (i < nvec0) is exactly batch 0
// and feeds the 12-bit high-bits histogram of |x[0]|.
__global__ __launch_bounds__(256) void silu_hist_kernel(const float4* __restrict__ x,
                                                        float4* __restrict__ out,
                                                        int nvec, int nvec0,
                                                        unsigned* __restrict__ gbins) {
  __shared__ unsigned lbins[NBINS];
  for (int j = threadIdx.x; j < NBINS; j += 256) lbins[j] = 0u;
  __syncthreads();

  int i = blockIdx.x * blockDim.x + threadIdx.x;
  int stride = gridDim.x * blockDim.x;
  for (; i < nvec; i += stride) {
    float4 v = x[i];
    float4 r;
    r.x = v.x * __builtin_amdgcn_rcpf(1.0f + __expf(-v.x));
    r.y = v.y * __builtin_amdgcn_rcpf(1.0f + __expf(-v.y));
    r.z = v.z * __builtin_amdgcn_rcpf(1.0f + __expf(-v.z));
    r.w = v.w * __builtin_amdgcn_rcpf(1.0f + __expf(-v.w));
    out[i] = r;
    if (i < nvec0) {
      unsigned a;
      a = __float_as_uint(v.x) & 0x7fffffffu; atomicAdd(&lbins[a >> 19], 1u);
      a = __float_as_uint(v.y) & 0x7fffffffu; atomicAdd(&lbins[a >> 19], 1u);
      a = __float_as_uint(v.z) & 0x7fffffffu; atomicAdd(&lbins[a >> 19], 1u);
      a = __float_as_uint(v.w) & 0x7fffffffu; atomicAdd(&lbins[a >> 19], 1u);
    }
  }
  __syncthreads();
  for (int j = threadIdx.x; j < NBINS; j += 256) {
    unsigned c = lbins[j];
    if (c) atomicAdd(&gbins[j], c);
  }
}

// ---------- in-block bin selection helper ----------
// All 256 threads participate. lbins[nbins] holds counts; finds the bin
// containing rank krem (1-indexed). Results in sel[0]=bin, sel[1]=rank-in-bin.
__device__ inline void select_bin(const unsigned* lbins, int nbins, unsigned krem,
                                  unsigned* csum, unsigned* sel) {
  const int t = threadIdx.x;
  const int per = (nbins + 255) >> 8;
  const int lo = t * per;
  const int hi = (lo + per < nbins) ? lo + per : nbins;
  unsigned s = 0;
  for (int j = lo; j < hi; ++j) s += lbins[j];
  csum[t] = s;
  __syncthreads();
  for (int off = 1; off < 256; off <<= 1) {
    unsigned add = (t >= off) ? csum[t - off] : 0u;
    __syncthreads();
    csum[t] += add;
    __syncthreads();
  }
  unsigned incl = csum[t], excl = incl - s;
  if (krem > excl && krem <= incl) {   // exactly one thread
    unsigned run = excl;
    for (int j = lo; j < hi; ++j) {
      unsigned c = lbins[j];
      if (krem <= run + c) { sel[0] = (unsigned)j; sel[1] = krem - run; break; }
      run += c;
    }
  }
  __syncthreads();
}

// ---------- pass-1 scan: pick high bin ----------
__global__ __launch_bounds__(256) void scan1_kernel(Ws* __restrict__ ws, unsigned k) {
  __shared__ unsigned csum[256];
  __shared__ unsigned sel[2];
  select_bin(ws->bins, NBINS, k, csum, sel);
  if (threadIdx.x == 0) { ws->b1 = sel[0]; ws->krem = sel[1]; }
}

// ---------- compaction: gather |x[0]| patterns in bin b1 ----------
__global__ __launch_bounds__(256) void compact_kernel(const uint4* __restrict__ x, int nvec0,
                                                      Ws* __restrict__ ws) {
  __shared__ unsigned lcand[1024];
  __shared__ unsigned lcnt, gbase;
  if (threadIdx.x == 0) lcnt = 0u;
  __syncthreads();
  const unsigned b1 = ws->b1;
  int i = blockIdx.x * blockDim.x + threadIdx.x;
  int stride = gridDim.x * blockDim.x;
  for (; i < nvec0; i += stride) {
    uint4 v = x[i];
    unsigned a;
    a = v.x & 0x7fffffffu; if ((a >> 19) == b1) { unsigned p = atomicAdd(&lcnt, 1u); if (p < 1024u) lcand[p] = a; }
    a = v.y & 0x7fffffffu; if ((a >> 19) == b1) { unsigned p = atomicAdd(&lcnt, 1u); if (p < 1024u) lcand[p] = a; }
    a = v.z & 0x7fffffffu; if ((a >> 19) == b1) { unsigned p = atomicAdd(&lcnt, 1u); if (p < 1024u) lcand[p] = a; }
    a = v.w & 0x7fffffffu; if ((a >> 19) == b1) { unsigned p = atomicAdd(&lcnt, 1u); if (p < 1024u) lcand[p] = a; }
  }
  __syncthreads();
  unsigned cnt = lcnt < 1024u ? lcnt : 1024u;
  if (threadIdx.x == 0 && cnt) gbase = atomicAdd(&ws->ncand, cnt);
  __syncthreads();
  for (unsigned j = threadIdx.x; j < cnt; j += 256) {
    unsigned g = gbase + j;
    if (g < (unsigned)CAP) ws->cand[g] = lcand[j];
  }
}

// ---------- final: radix-select remaining 19 bits over candidates ----------
__global__ __launch_bounds__(256) void final_kernel(Ws* __restrict__ ws,
                                                    float* __restrict__ out_scalars) {
  __shared__ unsigned lbins[NBINS];
  __shared__ unsigned csum[256];
  __shared__ unsigned sel[2];
  const int t = threadIdx.x;
  const unsigned nc = ws->ncand < (unsigned)CAP ? ws->ncand : (unsigned)CAP;
  const unsigned b1 = ws->b1;
  unsigned krem = ws->krem;

  // phase A: bits [18:7]
  for (int j = t; j < NBINS; j += 256) lbins[j] = 0u;
  __syncthreads();
  for (unsigned j = t; j < nc; j += 256) {
    unsigned a = ws->cand[j];
    atomicAdd(&lbins[(a >> 7) & 0xFFFu], 1u);
  }
  __syncthreads();
  select_bin(lbins, NBINS, krem, csum, sel);
  const unsigned b2 = sel[0];
  krem = sel[1];
  __syncthreads();

  // phase B: bits [6:0]
  for (int j = t; j < 128; j += 256) lbins[j] = 0u;
  __syncthreads();
  for (unsigned j = t; j < nc; j += 256) {
    unsigned a = ws->cand[j];
    if (((a >> 7) & 0xFFFu) == b2) atomicAdd(&lbins[a & 0x7Fu], 1u);
  }
  __syncthreads();
  select_bin(lbins, 128, krem, csum, sel);
  if (t == 0) {
    unsigned bits = (b1 << 19) | (b2 << 7) | sel[0];
    float v = __uint_as_float(bits);
    out_scalars[0] = v;           // outliner (exact k-th order statistic)
    out_scalars[1] = v / 127.0f;  // scale = max(|x_sub0|)/127 == outliner/127
  }
}

extern "C" void kernel_launch(void* const* d_in, const int* in_sizes, int n_in,
                              void* d_out, int out_size, void* d_ws, size_t ws_size,
                              hipStream_t stream) {
  const float* x = (const float*)d_in[0];
  float* out = (float*)d_out;
  const int n = in_sizes[0];     // 8*2048*4096
  const int n0 = n / 8;          // batch 0: 8388608
  const unsigned k = (unsigned)((double)n0 * 0.99);  // python int() truncation

  Ws* ws = (Ws*)d_ws;
  const int nvec = n / 4;
  const int nvec0 = n0 / 4;

  init_kernel<<<1, 256, 0, stream>>>(ws);
  // 8192 blocks * 256 threads = 2,097,152 = nvec0: iteration 0 covers batch 0 exactly
  silu_hist_kernel<<<8192, 256, 0, stream>>>((const float4*)x, (float4*)out,
                                             nvec, nvec0, ws->bins);
  scan1_kernel<<<1, 256, 0, stream>>>(ws, k);
  compact_kernel<<<2048, 256, 0, stream>>>((const uint4*)x, nvec0, ws);
  final_kernel<<<1, 256, 0, stream>>>(ws, out + n);
}